// Round 2
// 6856.487 us; speedup vs baseline: 1.0488x; 1.0488x over previous
//
#include <hip/hip_runtime.h>
#include <hip/hip_bf16.h>
#include <math.h>

// Problem dims (fixed by the reference)
#define T_  512
#define B_  64
#define I_  512
#define H_  1024
#define HX_ 1536
#define NG  4096          // 4*H packed gate rows
#define RP  17            // reduce-buffer pitch (fp32)
#define NBLK 512          // persistent grid: 2 blocks/CU * 256 CUs (co-resident by construction)

typedef __attribute__((ext_vector_type(8))) short bf16x8;
typedef __attribute__((ext_vector_type(4))) float floatx4;
typedef unsigned long long ull;

__device__ __forceinline__ float sigmoidf_(float v) { return 1.0f / (1.0f + __expf(-v)); }
__device__ __forceinline__ float tanhf_(float v) {
    float e = __expf(-2.0f * fabsf(v));
    float t = (1.0f - e) / (1.0f + e);
    return copysignf(t, v);
}
__device__ __forceinline__ short f2bf(float f) {
    union { __hip_bfloat16 b; short s; } u;
    u.b = __float2bfloat16(f);   // RNE
    return u.s;
}
__device__ __forceinline__ ull pack4bf(float a, float b, float c, float d) {
    return (ull)(unsigned short)f2bf(a)
         | ((ull)(unsigned short)f2bf(b) << 16)
         | ((ull)(unsigned short)f2bf(c) << 32)
         | ((ull)(unsigned short)f2bf(d) << 48);
}

// ---- prologue: pack Wg -> Wp [4096][HX] bf16, rows r = u*4+g; biases too ----
__global__ __launch_bounds__(256) void pack_w(
    const float* __restrict__ Wf, const float* __restrict__ Wi,
    const float* __restrict__ Wc, const float* __restrict__ Wo,
    const float* __restrict__ bf, const float* __restrict__ bi,
    const float* __restrict__ bc, const float* __restrict__ bo,
    short* __restrict__ Wp, float* __restrict__ bp)
{
    const int r = blockIdx.x;          // 0..4095
    const int u = r >> 2, g = r & 3;
    const float* src; const float* bsrc;
    switch (g) {
        case 0:  src = Wf; bsrc = bf; break;
        case 1:  src = Wi; bsrc = bi; break;
        case 2:  src = Wc; bsrc = bc; break;
        default: src = Wo; bsrc = bo; break;
    }
    src += (size_t)u * HX_;
    for (int off = threadIdx.x; off < HX_; off += 256)
        Wp[(size_t)r * HX_ + off] = f2bf(src[off]);
    if (threadIdx.x == 0) bp[r] = bsrc[u];
}

// ---- persistent-path init: stage bf16(x_t) into hxall[t] x-part for ALL t,
//      zero hxall[0] h-part, zero barrier counters ----
__global__ __launch_bounds__(256) void init_hxall(
    const float* __restrict__ x, short* __restrict__ hxall, unsigned* __restrict__ bar)
{
    const int idx = blockIdx.x * 256 + threadIdx.x;
    const int nx4 = T_ * B_ * I_ / 4;               // 4,194,304 quads
    if (idx < nx4) {
        const int e = idx * 4;                      // element index into x
        const int t = e >> 15;                      // / (B_*I_)
        const int r = e & (B_ * I_ - 1);
        const int b = r >> 9, p = r & 511;
        const float4 xv = *(const float4*)(x + (size_t)e);
        *(ull*)(hxall + (size_t)t * (B_ * HX_) + (size_t)b * HX_ + H_ + p)
            = pack4bf(xv.x, xv.y, xv.z, xv.w);
    } else if (idx < nx4 + B_ * H_ / 4) {           // zero slot-0 h-part
        const int k = (idx - nx4) * 4;
        const int b = k >> 10, p = k & 1023;
        *(ull*)(hxall + (size_t)b * HX_ + p) = 0ull;
    }
    if (idx < 256) bar[idx] = 0u;
}

// ---- persistent LSTM: all 512 timesteps in one PLAIN-launched kernel ----
// Grid = 512 blocks x 512 thr; __launch_bounds__(512,4) caps VGPR at 128 so
// 2 blocks/CU is compiler-guaranteed -> 512 blocks == device capacity -> all
// blocks resident at launch (no cooperative API, graph-capture-safe).
// Wave decomposition identical to the proven per-step kernel. Weights pinned
// in VGPRs; c and bias in registers. h_t published to hxall[t+1] via
// device-scope 8B stores (fresh, 128B-aligned addresses each step -> no stale
// cache lines anywhere, no flushes needed). Grid barrier = 8 sharded
// monotonic counters + bounded poll (watchdog: terminates instead of hanging).
__global__ __launch_bounds__(512, 4) void lstm_all(
    const short* __restrict__ Wp, const float* __restrict__ bp,
    short* __restrict__ hxall,            // [T_+1][B_][HX_] bf16
    unsigned* __restrict__ bar,           // 8 shard counters, 128B apart
    float* __restrict__ out)              // [T_][B_][H_]
{
    __shared__ __align__(16) float red[4 * 32 * RP];

    const int tid  = threadIdx.x;
    const int bid  = blockIdx.x;          // 0..511
    const int nt   = bid & 255;
    const int mh   = bid >> 8;
    const int lane = tid & 63;
    const int wv   = tid >> 6;            // 0..7
    const int w    = wv & 1;
    const int kq   = wv >> 1;
    const int n16  = lane & 15;
    const int quad = lane >> 4;
    const int n0   = nt * 16;
    const int j0   = nt * 4;
    const int mrow = mh * 32 + w * 16 + n16;

    // Weights: load once, keep in VGPRs for all 512 steps.
    bf16x8 bfr[12];
    {
        const short* brow = Wp + (size_t)(n0 + n16) * HX_ + kq * 384 + quad * 8;
        #pragma unroll
        for (int i = 0; i < 12; ++i) bfr[i] = *(const bf16x8*)(brow + i * 32);
    }

    // Epilogue-role constants (tid < 128): thread = (batch b_loc, unit j0+u)
    const int b_loc = tid >> 2;
    const int u     = tid & 3;
    const int gb    = mh * 32 + b_loc;
    const float4 bias = *(const float4*)(bp + n0 + u * 4);
    float c = 0.0f;

    // Running pointers (advance by one time-slot per step)
    const short* ap = hxall + (size_t)mrow * HX_ + kq * 384 + quad * 8;     // A src (slot t)
    ull* hd = (ull*)(hxall + (size_t)(B_ * HX_) + (size_t)gb * HX_ + j0);   // h dst (slot t+1)
    float* op = out + (size_t)gb * H_ + j0 + u;

    unsigned* shardp = bar + (unsigned)(bid & 7) * 32;

    for (int t = 0; t < T_; ++t) {
        // A prefetch pipeline + 12 MFMAs (identical to the proven kernel)
        bf16x8 afr[4];
        #pragma unroll
        for (int i = 0; i < 4; ++i) afr[i] = *(const bf16x8*)(ap + i * 32);
        floatx4 acc = {0.f, 0.f, 0.f, 0.f};
        #pragma unroll
        for (int kf = 0; kf < 12; ++kf) {
            acc = __builtin_amdgcn_mfma_f32_16x16x32_bf16(afr[kf & 3], bfr[kf], acc, 0, 0, 0);
            if (kf + 4 < 12) afr[kf & 3] = *(const bf16x8*)(ap + (kf + 4) * 32);
        }

        // C/D layout: col = lane&15, row = quad*4 + reg
        #pragma unroll
        for (int i2 = 0; i2 < 4; ++i2)
            red[(kq * 32 + w * 16 + quad * 4 + i2) * RP + n16] = acc[i2];
        __syncthreads();

        if (tid < 128) {
            float gv[4];
            #pragma unroll
            for (int gg = 0; gg < 4; ++gg) {
                const int col = u * 4 + gg;
                gv[gg] = red[(0 * 32 + b_loc) * RP + col]
                       + red[(1 * 32 + b_loc) * RP + col]
                       + red[(2 * 32 + b_loc) * RP + col]
                       + red[(3 * 32 + b_loc) * RP + col];
            }
            const float F  = sigmoidf_(gv[0] + bias.x);
            const float In = sigmoidf_(gv[1] + bias.y);
            const float G  = tanhf_(gv[2] + bias.z);
            const float O  = sigmoidf_(gv[3] + bias.w);
            c = F * c + In * G;
            const float h = O * tanhf_(c);
            *op = h;
            // gather the 4 units of this (batch, j0-block) into one 8B
            // device-coherent store (lanes u=0..3 are adjacent)
            const int hv = (int)(unsigned short)f2bf(h);
            const int base = lane & ~3;
            const int a0 = __shfl(hv, base + 0);
            const int a1 = __shfl(hv, base + 1);
            const int a2 = __shfl(hv, base + 2);
            const int a3 = __shfl(hv, base + 3);
            if (u == 0) {
                const ull pk = (ull)(unsigned)(unsigned short)a0
                             | ((ull)(unsigned)(unsigned short)a1 << 16)
                             | ((ull)(unsigned)(unsigned short)a2 << 32)
                             | ((ull)(unsigned)(unsigned short)a3 << 48);
                __hip_atomic_store(hd, pk, __ATOMIC_RELAXED, __HIP_MEMORY_SCOPE_AGENT);
            }
        }
        // Drain all stores (compiler emits s_waitcnt vmcnt(0) before s_barrier),
        // THEN signal arrival -> h is durable at the coherence point first.
        __syncthreads();

        if (t + 1 < T_) {
            if (tid == 0) {
                __hip_atomic_fetch_add(shardp, 1u, __ATOMIC_RELAXED,
                                       __HIP_MEMORY_SCOPE_AGENT);
                const unsigned tgt = 64u * (unsigned)(t + 1);
                // Bounded poll: ~2M rounds (~0.5 s) >> worst legit skew (~tens
                // of us). On true deadlock we exit -> wrong answer, NOT a hang.
                for (unsigned it = 0; it < (1u << 21); ++it) {
                    unsigned ok = 1u;
                    #pragma unroll
                    for (int s = 0; s < 8; ++s)
                        ok &= (__hip_atomic_load(bar + s * 32, __ATOMIC_RELAXED,
                                   __HIP_MEMORY_SCOPE_AGENT) >= tgt) ? 1u : 0u;
                    if (ok) break;
                    __builtin_amdgcn_s_sleep(2);
                }
            }
            __syncthreads();
        }

        ap += B_ * HX_;
        hd += (B_ * HX_) / 4;     // ull increments
        op += B_ * H_;
    }
}

// ================= fallback path (proven multi-launch kernels) =================

__global__ __launch_bounds__(256) void init_all(
    const float* __restrict__ x0, short* __restrict__ hx0, float* __restrict__ cws)
{
    int idx = blockIdx.x * 256 + threadIdx.x;
    if (idx < B_ * HX_) {
        int b = idx / HX_, p = idx % HX_;
        hx0[idx] = (p < H_) ? (short)0 : f2bf(x0[b * I_ + (p - H_)]);
    } else if (idx < B_ * HX_ + 512 * 128) {
        cws[idx - B_ * HX_] = 0.0f;
    }
}

__global__ __launch_bounds__(512, 4) void lstm_step(
    const short* __restrict__ Wp, const float* __restrict__ bp,
    const short* __restrict__ hxsrc, short* __restrict__ hxdst,
    const float* __restrict__ xnext, float* __restrict__ cws,
    float* __restrict__ out_t)
{
    __shared__ __align__(16) float red[4 * 32 * RP];

    const int tid  = threadIdx.x;
    const int nt   = blockIdx.x;
    const int mh   = blockIdx.y;
    const int lane = tid & 63;
    const int wv   = tid >> 6;
    const int w    = wv & 1;
    const int kq   = wv >> 1;
    const int n16  = lane & 15;
    const int quad = lane >> 4;
    const int n0   = nt * 16;
    const int j0   = nt * 4;
    const int mrow = mh * 32 + w * 16 + n16;

    const short* __restrict__ arow = hxsrc + mrow * HX_ + kq * 384 + quad * 8;
    const short* __restrict__ brow = Wp + (size_t)(n0 + n16) * HX_ + kq * 384 + quad * 8;

    bf16x8 bfr[12];
    #pragma unroll
    for (int i = 0; i < 12; ++i) bfr[i] = *(const bf16x8*)(brow + i * 32);
    bf16x8 afr[4];
    #pragma unroll
    for (int i = 0; i < 4; ++i) afr[i] = *(const bf16x8*)(arow + i * 32);

    floatx4 acc = {0.f, 0.f, 0.f, 0.f};
    #pragma unroll
    for (int kf = 0; kf < 12; ++kf) {
        acc = __builtin_amdgcn_mfma_f32_16x16x32_bf16(afr[kf & 3], bfr[kf], acc, 0, 0, 0);
        if (kf + 4 < 12) afr[kf & 3] = *(const bf16x8*)(arow + (kf + 4) * 32);
    }

    #pragma unroll
    for (int i2 = 0; i2 < 4; ++i2)
        red[(kq * 32 + w * 16 + quad * 4 + i2) * RP + n16] = acc[i2];
    __syncthreads();

    if (tid < 128) {
        const int b_loc = tid >> 2, u = tid & 3;
        float4 bias = *(const float4*)(bp + n0 + u * 4);
        float gv[4];
        #pragma unroll
        for (int gg = 0; gg < 4; ++gg) {
            const int col = u * 4 + gg;
            float s = red[(0 * 32 + b_loc) * RP + col]
                    + red[(1 * 32 + b_loc) * RP + col]
                    + red[(2 * 32 + b_loc) * RP + col]
                    + red[(3 * 32 + b_loc) * RP + col];
            gv[gg] = s;
        }
        float F  = sigmoidf_(gv[0] + bias.x);
        float In = sigmoidf_(gv[1] + bias.y);
        float G  = tanhf_(gv[2] + bias.z);
        float O  = sigmoidf_(gv[3] + bias.w);
        const int cidx = (mh * 256 + nt) * 128 + tid;
        float c = cws[cidx];
        c = F * c + In * G;
        cws[cidx] = c;
        float h = O * tanhf_(c);
        const int gb = mh * 32 + b_loc;
        out_t[(size_t)gb * H_ + j0 + u] = h;
        hxdst[gb * HX_ + j0 + u] = f2bf(h);
    } else if (tid < 192) {
        if (xnext) {
            const int e = (mh * 256 + nt) * 64 + (tid - 128);
            const int b = e >> 9, p = e & 511;
            hxdst[b * HX_ + H_ + p] = f2bf(xnext[e]);
        }
    }
}

// ================================ launcher ================================

extern "C" void kernel_launch(void* const* d_in, const int* in_sizes, int n_in,
                              void* d_out, int out_size, void* d_ws, size_t ws_size,
                              hipStream_t stream) {
    const float* x  = (const float*)d_in[0];
    const float* Wf = (const float*)d_in[1];
    const float* bf = (const float*)d_in[2];
    const float* Wi = (const float*)d_in[3];
    const float* bi = (const float*)d_in[4];
    const float* Wc = (const float*)d_in[5];
    const float* bc = (const float*)d_in[6];
    const float* Wo = (const float*)d_in[7];
    const float* bo = (const float*)d_in[8];
    float* out = (float*)d_out;

    // ws layout (bytes):
    //   Wp    : 4096*1536*2      = 12,582,912
    //   bp    : 4096*4           =     16,384
    //   bar   : 4,096 (8 counters, 128B apart)
    //   hx0/1 : 2*64*1536*2      =    393,216   (fallback)
    //   cws   : 512*128*4        =    262,144   (fallback)
    //   hxall : 513*64*1536*2    = 100,859,904  (persistent)  -> total ~114.1 MB
    char* wsb = (char*)d_ws;
    size_t off = 0;
    short*    Wp    = (short*)(wsb + off);    off += (size_t)NG * HX_ * 2;
    float*    bp    = (float*)(wsb + off);    off += (size_t)NG * 4;
    unsigned* bar   = (unsigned*)(wsb + off); off += 4096;
    short*    hx0   = (short*)(wsb + off);    off += (size_t)B_ * HX_ * 2;
    short*    hx1   = (short*)(wsb + off);    off += (size_t)B_ * HX_ * 2;
    float*    cws   = (float*)(wsb + off);    off += (size_t)512 * 128 * 4;
    short*    hxall = (short*)(wsb + off);
    const size_t need = off + (size_t)(T_ + 1) * B_ * HX_ * 2;

    pack_w<<<NG, 256, 0, stream>>>(Wf, Wi, Wc, Wo, bf, bi, bc, bo, Wp, bp);

    if (ws_size >= need) {
        const int nx4 = T_ * B_ * I_ / 4;
        init_hxall<<<(nx4 + B_ * H_ / 4 + 255) / 256, 256, 0, stream>>>(x, hxall, bar);
        lstm_all<<<dim3(NBLK), dim3(512), 0, stream>>>(Wp, bp, hxall, bar, out);
        return;
    }

    init_all<<<(B_ * HX_ + 512 * 128 + 255) / 256, 256, 0, stream>>>(x, hx0, cws);
    for (int t = 0; t < T_; ++t) {
        const short* hxsrc = (t & 1) ? hx1 : hx0;
        short*       hxdst = (t & 1) ? hx0 : hx1;
        const float* xnext = (t + 1 < T_) ? (x + (size_t)(t + 1) * B_ * I_) : nullptr;
        lstm_step<<<dim3(256, 2), 512, 0, stream>>>(
            Wp, bp, hxsrc, hxdst, xnext, cws,
            out + (size_t)t * B_ * H_);
    }
}

// Round 3
// 4102.437 us; speedup vs baseline: 1.7529x; 1.6713x over previous
//
#include <hip/hip_runtime.h>
#include <hip/hip_bf16.h>
#include <math.h>

// Problem dims (fixed by the reference)
#define T_  512
#define B_  64
#define I_  512
#define H_  1024
#define HX_ 1536
#define NG  4096          // 4*H packed gate rows
#define RP  17            // reduce-buffer pitch (fp32)
#define NBLK 512          // persistent grid: 2 blocks/CU * 256 CUs (co-resident by construction)

// Barrier layout (uints, 128B lines = 32 uints):
//   flag[bid]   : line bid            (512 lines)
//   epoch[g][r] : line 512 + g*8 + r  (16 lines, g=group/mh, r=replica)
#define EPOCH_OFF (512 * 32)
#define BAR_INTS  (512 * 32 + 16 * 32)   // 16,896 uints = 67,584 B

typedef __attribute__((ext_vector_type(8))) short bf16x8;
typedef __attribute__((ext_vector_type(4))) float floatx4;
typedef unsigned long long ull;

__device__ __forceinline__ float sigmoidf_(float v) { return 1.0f / (1.0f + __expf(-v)); }
__device__ __forceinline__ float tanhf_(float v) {
    float e = __expf(-2.0f * fabsf(v));
    float t = (1.0f - e) / (1.0f + e);
    return copysignf(t, v);
}
__device__ __forceinline__ short f2bf(float f) {
    union { __hip_bfloat16 b; short s; } u;
    u.b = __float2bfloat16(f);   // RNE
    return u.s;
}
__device__ __forceinline__ ull pack4bf(float a, float b, float c, float d) {
    return (ull)(unsigned short)f2bf(a)
         | ((ull)(unsigned short)f2bf(b) << 16)
         | ((ull)(unsigned short)f2bf(c) << 32)
         | ((ull)(unsigned short)f2bf(d) << 48);
}

// ---- prologue: pack Wg -> Wp [4096][HX] bf16, rows r = u*4+g; biases too ----
__global__ __launch_bounds__(256) void pack_w(
    const float* __restrict__ Wf, const float* __restrict__ Wi,
    const float* __restrict__ Wc, const float* __restrict__ Wo,
    const float* __restrict__ bf, const float* __restrict__ bi,
    const float* __restrict__ bc, const float* __restrict__ bo,
    short* __restrict__ Wp, float* __restrict__ bp)
{
    const int r = blockIdx.x;          // 0..4095
    const int u = r >> 2, g = r & 3;
    const float* src; const float* bsrc;
    switch (g) {
        case 0:  src = Wf; bsrc = bf; break;
        case 1:  src = Wi; bsrc = bi; break;
        case 2:  src = Wc; bsrc = bc; break;
        default: src = Wo; bsrc = bo; break;
    }
    src += (size_t)u * HX_;
    for (int off = threadIdx.x; off < HX_; off += 256)
        Wp[(size_t)r * HX_ + off] = f2bf(src[off]);
    if (threadIdx.x == 0) bp[r] = bsrc[u];
}

// ---- persistent-path init: stage bf16(x_t) into hxall[t] x-part for ALL t,
//      zero hxall[0] h-part, zero barrier flags/epochs ----
__global__ __launch_bounds__(256) void init_hxall(
    const float* __restrict__ x, short* __restrict__ hxall, unsigned* __restrict__ bar)
{
    const int idx = blockIdx.x * 256 + threadIdx.x;
    const int nx4 = T_ * B_ * I_ / 4;               // 4,194,304 quads
    if (idx < nx4) {
        const int e = idx * 4;                      // element index into x
        const int t = e >> 15;                      // / (B_*I_)
        const int r = e & (B_ * I_ - 1);
        const int b = r >> 9, p = r & 511;
        const float4 xv = *(const float4*)(x + (size_t)e);
        *(ull*)(hxall + (size_t)t * (B_ * HX_) + (size_t)b * HX_ + H_ + p)
            = pack4bf(xv.x, xv.y, xv.z, xv.w);
    } else if (idx < nx4 + B_ * H_ / 4) {           // zero slot-0 h-part
        const int k = (idx - nx4) * 4;
        const int b = k >> 10, p = k & 1023;
        *(ull*)(hxall + (size_t)b * HX_ + p) = 0ull;
    }
    if (idx < BAR_INTS) bar[idx] = 0u;
}

// ---- persistent LSTM: all 512 timesteps in one PLAIN-launched kernel ----
// Grid = 512 x 512thr, __launch_bounds__(512,4) -> 2 blocks/CU guaranteed ->
// all blocks resident at launch. Weights pinned in VGPRs; c in registers;
// h_t published via device-scope 8B stores into the T-expanded hxall (fresh
// 128B-aligned lines each step -> no stale-cache hazard, no flushes).
//
// Grid barrier (per mh-group of 256 blocks, the two groups are independent):
//   arrive : tid0 stores flag[bid]=t+1 (own line, plain agent store, no RMW)
//   master : block nt==0, wave0 polls its group's 256 flags (4/lane, __all),
//            then lanes 0..7 store epoch[g] replicated on 8 lines
//   waiters: tid0 polls its epoch replica (1 hot line/round, sharded bid&7)
// Bounded polls (2^16 rounds ~ 8ms/step) -> terminates instead of hanging.
__global__ __launch_bounds__(512, 4) void lstm_all(
    const short* __restrict__ Wp, const float* __restrict__ bp,
    short* __restrict__ hxall,            // [T_+1][B_][HX_] bf16
    unsigned* __restrict__ bar,
    float* __restrict__ out)              // [T_][B_][H_]
{
    __shared__ __align__(16) float red[4 * 32 * RP];

    const int tid  = threadIdx.x;
    const int bid  = blockIdx.x;          // 0..511
    const int nt   = bid & 255;
    const int mh   = bid >> 8;
    const int lane = tid & 63;
    const int wv   = tid >> 6;            // 0..7
    const int w    = wv & 1;
    const int kq   = wv >> 1;
    const int n16  = lane & 15;
    const int quad = lane >> 4;
    const int n0   = nt * 16;
    const int j0   = nt * 4;
    const int mrow = mh * 32 + w * 16 + n16;

    // Weights: load once, keep in registers for all 512 steps.
    bf16x8 bfr[12];
    {
        const short* brow = Wp + (size_t)(n0 + n16) * HX_ + kq * 384 + quad * 8;
        #pragma unroll
        for (int i = 0; i < 12; ++i) bfr[i] = *(const bf16x8*)(brow + i * 32);
    }

    // Epilogue-role constants (tid < 128): thread = (batch b_loc, unit j0+u)
    const int b_loc = tid >> 2;
    const int u     = tid & 3;
    const int gb    = mh * 32 + b_loc;
    const float4 bias = *(const float4*)(bp + n0 + u * 4);
    float c = 0.0f;

    // Running pointers (advance by one time-slot per step)
    const short* ap = hxall + (size_t)mrow * HX_ + kq * 384 + quad * 8;     // A src (slot t)
    ull* hd = (ull*)(hxall + (size_t)(B_ * HX_) + (size_t)gb * HX_ + j0);   // h dst (slot t+1)
    float* op = out + (size_t)gb * H_ + j0 + u;

    unsigned* const flagp  = bar + (unsigned)bid * 32;                         // own line
    const unsigned* const epochp = bar + EPOCH_OFF + (mh * 8 + (bid & 7)) * 32; // shared hot line

    for (int t = 0; t < T_; ++t) {
        // A prefetch pipeline + 12 MFMAs (identical to the proven kernel)
        bf16x8 afr[4];
        #pragma unroll
        for (int i = 0; i < 4; ++i) afr[i] = *(const bf16x8*)(ap + i * 32);
        floatx4 acc = {0.f, 0.f, 0.f, 0.f};
        #pragma unroll
        for (int kf = 0; kf < 12; ++kf) {
            acc = __builtin_amdgcn_mfma_f32_16x16x32_bf16(afr[kf & 3], bfr[kf], acc, 0, 0, 0);
            if (kf + 4 < 12) afr[kf & 3] = *(const bf16x8*)(ap + (kf + 4) * 32);
        }

        // C/D layout: col = lane&15, row = quad*4 + reg
        #pragma unroll
        for (int i2 = 0; i2 < 4; ++i2)
            red[(kq * 32 + w * 16 + quad * 4 + i2) * RP + n16] = acc[i2];
        __syncthreads();

        if (tid < 128) {
            float gv[4];
            #pragma unroll
            for (int gg = 0; gg < 4; ++gg) {
                const int col = u * 4 + gg;
                gv[gg] = red[(0 * 32 + b_loc) * RP + col]
                       + red[(1 * 32 + b_loc) * RP + col]
                       + red[(2 * 32 + b_loc) * RP + col]
                       + red[(3 * 32 + b_loc) * RP + col];
            }
            const float F  = sigmoidf_(gv[0] + bias.x);
            const float In = sigmoidf_(gv[1] + bias.y);
            const float G  = tanhf_(gv[2] + bias.z);
            const float O  = sigmoidf_(gv[3] + bias.w);
            c = F * c + In * G;
            const float h = O * tanhf_(c);
            *op = h;
            // gather the 4 units of this (batch, j0-block) into one 8B
            // device-coherent store (lanes u=0..3 are adjacent)
            const int hv = (int)(unsigned short)f2bf(h);
            const int base = lane & ~3;
            const int a0 = __shfl(hv, base + 0);
            const int a1 = __shfl(hv, base + 1);
            const int a2 = __shfl(hv, base + 2);
            const int a3 = __shfl(hv, base + 3);
            if (u == 0) {
                const ull pk = (ull)(unsigned)(unsigned short)a0
                             | ((ull)(unsigned)(unsigned short)a1 << 16)
                             | ((ull)(unsigned)(unsigned short)a2 << 32)
                             | ((ull)(unsigned)(unsigned short)a3 << 48);
                __hip_atomic_store(hd, pk, __ATOMIC_RELAXED, __HIP_MEMORY_SCOPE_AGENT);
            }
        }
        // Drain all stores (s_waitcnt vmcnt(0) before s_barrier), THEN arrive:
        // h is durable at the coherence point before the flag becomes visible.
        __syncthreads();

        if (t + 1 < T_) {
            const unsigned tgt = (unsigned)(t + 1);
            if (tid == 0)
                __hip_atomic_store(flagp, tgt, __ATOMIC_RELAXED,
                                   __HIP_MEMORY_SCOPE_AGENT);
            if (nt == 0) {
                // master: wave0 polls this group's 256 flags, 4 per lane
                if (tid < 64) {
                    const unsigned* f0 = bar + (mh * 256 + tid * 4) * 32;
                    for (unsigned it = 0; it < (1u << 16); ++it) {
                        const unsigned v0 = __hip_atomic_load(f0 +  0, __ATOMIC_RELAXED, __HIP_MEMORY_SCOPE_AGENT);
                        const unsigned v1 = __hip_atomic_load(f0 + 32, __ATOMIC_RELAXED, __HIP_MEMORY_SCOPE_AGENT);
                        const unsigned v2 = __hip_atomic_load(f0 + 64, __ATOMIC_RELAXED, __HIP_MEMORY_SCOPE_AGENT);
                        const unsigned v3 = __hip_atomic_load(f0 + 96, __ATOMIC_RELAXED, __HIP_MEMORY_SCOPE_AGENT);
                        const int ok = (v0 >= tgt) && (v1 >= tgt) && (v2 >= tgt) && (v3 >= tgt);
                        if (__all(ok)) break;
                        __builtin_amdgcn_s_sleep(1);
                    }
                    // broadcast release, replicated across 8 lines
                    if (tid < 8)
                        __hip_atomic_store(bar + EPOCH_OFF + (mh * 8 + tid) * 32, tgt,
                                           __ATOMIC_RELAXED, __HIP_MEMORY_SCOPE_AGENT);
                }
                __syncthreads();
            } else {
                if (tid == 0) {
                    for (unsigned it = 0; it < (1u << 16); ++it) {
                        if (__hip_atomic_load(epochp, __ATOMIC_RELAXED,
                                              __HIP_MEMORY_SCOPE_AGENT) >= tgt) break;
                        __builtin_amdgcn_s_sleep(1);
                    }
                }
                __syncthreads();
            }
        }

        ap += B_ * HX_;
        hd += (B_ * HX_) / 4;     // ull increments
        op += B_ * H_;
    }
}

// ================= fallback path (proven multi-launch kernels) =================

__global__ __launch_bounds__(256) void init_all(
    const float* __restrict__ x0, short* __restrict__ hx0, float* __restrict__ cws)
{
    int idx = blockIdx.x * 256 + threadIdx.x;
    if (idx < B_ * HX_) {
        int b = idx / HX_, p = idx % HX_;
        hx0[idx] = (p < H_) ? (short)0 : f2bf(x0[b * I_ + (p - H_)]);
    } else if (idx < B_ * HX_ + 512 * 128) {
        cws[idx - B_ * HX_] = 0.0f;
    }
}

__global__ __launch_bounds__(512, 4) void lstm_step(
    const short* __restrict__ Wp, const float* __restrict__ bp,
    const short* __restrict__ hxsrc, short* __restrict__ hxdst,
    const float* __restrict__ xnext, float* __restrict__ cws,
    float* __restrict__ out_t)
{
    __shared__ __align__(16) float red[4 * 32 * RP];

    const int tid  = threadIdx.x;
    const int nt   = blockIdx.x;
    const int mh   = blockIdx.y;
    const int lane = tid & 63;
    const int wv   = tid >> 6;
    const int w    = wv & 1;
    const int kq   = wv >> 1;
    const int n16  = lane & 15;
    const int quad = lane >> 4;
    const int n0   = nt * 16;
    const int j0   = nt * 4;
    const int mrow = mh * 32 + w * 16 + n16;

    const short* __restrict__ arow = hxsrc + mrow * HX_ + kq * 384 + quad * 8;
    const short* __restrict__ brow = Wp + (size_t)(n0 + n16) * HX_ + kq * 384 + quad * 8;

    bf16x8 bfr[12];
    #pragma unroll
    for (int i = 0; i < 12; ++i) bfr[i] = *(const bf16x8*)(brow + i * 32);
    bf16x8 afr[4];
    #pragma unroll
    for (int i = 0; i < 4; ++i) afr[i] = *(const bf16x8*)(arow + i * 32);

    floatx4 acc = {0.f, 0.f, 0.f, 0.f};
    #pragma unroll
    for (int kf = 0; kf < 12; ++kf) {
        acc = __builtin_amdgcn_mfma_f32_16x16x32_bf16(afr[kf & 3], bfr[kf], acc, 0, 0, 0);
        if (kf + 4 < 12) afr[kf & 3] = *(const bf16x8*)(arow + (kf + 4) * 32);
    }

    #pragma unroll
    for (int i2 = 0; i2 < 4; ++i2)
        red[(kq * 32 + w * 16 + quad * 4 + i2) * RP + n16] = acc[i2];
    __syncthreads();

    if (tid < 128) {
        const int b_loc = tid >> 2, u = tid & 3;
        float4 bias = *(const float4*)(bp + n0 + u * 4);
        float gv[4];
        #pragma unroll
        for (int gg = 0; gg < 4; ++gg) {
            const int col = u * 4 + gg;
            float s = red[(0 * 32 + b_loc) * RP + col]
                    + red[(1 * 32 + b_loc) * RP + col]
                    + red[(2 * 32 + b_loc) * RP + col]
                    + red[(3 * 32 + b_loc) * RP + col];
            gv[gg] = s;
        }
        float F  = sigmoidf_(gv[0] + bias.x);
        float In = sigmoidf_(gv[1] + bias.y);
        float G  = tanhf_(gv[2] + bias.z);
        float O  = sigmoidf_(gv[3] + bias.w);
        const int cidx = (mh * 256 + nt) * 128 + tid;
        float c = cws[cidx];
        c = F * c + In * G;
        cws[cidx] = c;
        float h = O * tanhf_(c);
        const int gb = mh * 32 + b_loc;
        out_t[(size_t)gb * H_ + j0 + u] = h;
        hxdst[gb * HX_ + j0 + u] = f2bf(h);
    } else if (tid < 192) {
        if (xnext) {
            const int e = (mh * 256 + nt) * 64 + (tid - 128);
            const int b = e >> 9, p = e & 511;
            hxdst[b * HX_ + H_ + p] = f2bf(xnext[e]);
        }
    }
}

// ================================ launcher ================================

extern "C" void kernel_launch(void* const* d_in, const int* in_sizes, int n_in,
                              void* d_out, int out_size, void* d_ws, size_t ws_size,
                              hipStream_t stream) {
    const float* x  = (const float*)d_in[0];
    const float* Wf = (const float*)d_in[1];
    const float* bf = (const float*)d_in[2];
    const float* Wi = (const float*)d_in[3];
    const float* bi = (const float*)d_in[4];
    const float* Wc = (const float*)d_in[5];
    const float* bc = (const float*)d_in[6];
    const float* Wo = (const float*)d_in[7];
    const float* bo = (const float*)d_in[8];
    float* out = (float*)d_out;

    // ws layout (bytes):
    //   Wp    : 4096*1536*2      = 12,582,912
    //   bp    : 4096*4           =     16,384
    //   bar   : 16896*4          =     67,584
    //   hx0/1 : 2*64*1536*2      =    393,216   (fallback)
    //   cws   : 512*128*4        =    262,144   (fallback)
    //   hxall : 513*64*1536*2    = 100,859,904  (persistent)  -> total ~114.2 MB
    char* wsb = (char*)d_ws;
    size_t off = 0;
    short*    Wp    = (short*)(wsb + off);    off += (size_t)NG * HX_ * 2;
    float*    bp    = (float*)(wsb + off);    off += (size_t)NG * 4;
    unsigned* bar   = (unsigned*)(wsb + off); off += (size_t)BAR_INTS * 4;
    short*    hx0   = (short*)(wsb + off);    off += (size_t)B_ * HX_ * 2;
    short*    hx1   = (short*)(wsb + off);    off += (size_t)B_ * HX_ * 2;
    float*    cws   = (float*)(wsb + off);    off += (size_t)512 * 128 * 4;
    short*    hxall = (short*)(wsb + off);
    const size_t need = off + (size_t)(T_ + 1) * B_ * HX_ * 2;

    pack_w<<<NG, 256, 0, stream>>>(Wf, Wi, Wc, Wo, bf, bi, bc, bo, Wp, bp);

    if (ws_size >= need) {
        const int nx4 = T_ * B_ * I_ / 4;
        init_hxall<<<(nx4 + B_ * H_ / 4 + 255) / 256, 256, 0, stream>>>(x, hxall, bar);
        lstm_all<<<dim3(NBLK), dim3(512), 0, stream>>>(Wp, bp, hxall, bar, out);
        return;
    }

    init_all<<<(B_ * HX_ + 512 * 128 + 255) / 256, 256, 0, stream>>>(x, hx0, cws);
    for (int t = 0; t < T_; ++t) {
        const short* hxsrc = (t & 1) ? hx1 : hx0;
        short*       hxdst = (t & 1) ? hx0 : hx1;
        const float* xnext = (t + 1 < T_) ? (x + (size_t)(t + 1) * B_ * I_) : nullptr;
        lstm_step<<<dim3(256, 2), 512, 0, stream>>>(
            Wp, bp, hxsrc, hxdst, xnext, cws,
            out + (size_t)t * B_ * H_);
    }
}

// Round 5
// 3440.994 us; speedup vs baseline: 2.0899x; 1.1922x over previous
//
#include <hip/hip_runtime.h>
#include <hip/hip_bf16.h>
#include <math.h>

// Problem dims (fixed by the reference)
#define T_  512
#define B_  64
#define I_  512
#define H_  1024
#define HX_ 1536
#define NG  4096          // 4*H packed gate rows
#define RP  17            // reduce-buffer pitch (fp32)
#define NBLK 512          // persistent grid: 2 blocks/CU * 256 CUs (co-resident by construction)

// Barrier layout (uints, 128B lines = 32 uints):
//   flag[bid]   : line bid            (512 lines)
//   epoch[g][r] : line 512 + g*8 + r  (16 lines, g=group/mh, r=replica)
#define EPOCH_OFF (512 * 32)
#define BAR_INTS  (512 * 32 + 16 * 32)   // 16,896 uints = 67,584 B

typedef __attribute__((ext_vector_type(8))) short bf16x8;
typedef __attribute__((ext_vector_type(4))) float floatx4;
typedef unsigned long long ull;

__device__ __forceinline__ float sigmoidf_(float v) { return 1.0f / (1.0f + __expf(-v)); }
__device__ __forceinline__ float tanhf_(float v) {
    float e = __expf(-2.0f * fabsf(v));
    float t = (1.0f - e) / (1.0f + e);
    return copysignf(t, v);
}
__device__ __forceinline__ short f2bf(float f) {
    union { __hip_bfloat16 b; short s; } u;
    u.b = __float2bfloat16(f);   // RNE
    return u.s;
}
__device__ __forceinline__ ull pack4bf(float a, float b, float c, float d) {
    return (ull)(unsigned short)f2bf(a)
         | ((ull)(unsigned short)f2bf(b) << 16)
         | ((ull)(unsigned short)f2bf(c) << 32)
         | ((ull)(unsigned short)f2bf(d) << 48);
}

// ---- prologue: pack Wg -> Wp [4096][HX] bf16, rows r = u*4+g; biases too ----
__global__ __launch_bounds__(256) void pack_w(
    const float* __restrict__ Wf, const float* __restrict__ Wi,
    const float* __restrict__ Wc, const float* __restrict__ Wo,
    const float* __restrict__ bf, const float* __restrict__ bi,
    const float* __restrict__ bc, const float* __restrict__ bo,
    short* __restrict__ Wp, float* __restrict__ bp)
{
    const int r = blockIdx.x;          // 0..4095
    const int u = r >> 2, g = r & 3;
    const float* src; const float* bsrc;
    switch (g) {
        case 0:  src = Wf; bsrc = bf; break;
        case 1:  src = Wi; bsrc = bi; break;
        case 2:  src = Wc; bsrc = bc; break;
        default: src = Wo; bsrc = bo; break;
    }
    src += (size_t)u * HX_;
    for (int off = threadIdx.x; off < HX_; off += 256)
        Wp[(size_t)r * HX_ + off] = f2bf(src[off]);
    if (threadIdx.x == 0) bp[r] = bsrc[u];
}

// ---- persistent-path init: stage bf16(x_t) into hxall[t] x-part for ALL t,
//      zero hxall[0] h-part, zero barrier flags/epochs ----
__global__ __launch_bounds__(256) void init_hxall(
    const float* __restrict__ x, short* __restrict__ hxall, unsigned* __restrict__ bar)
{
    const int idx = blockIdx.x * 256 + threadIdx.x;
    const int nx4 = T_ * B_ * I_ / 4;               // 4,194,304 quads
    if (idx < nx4) {
        const int e = idx * 4;                      // element index into x
        const int t = e >> 15;                      // / (B_*I_)
        const int r = e & (B_ * I_ - 1);
        const int b = r >> 9, p = r & 511;
        const float4 xv = *(const float4*)(x + (size_t)e);
        *(ull*)(hxall + (size_t)t * (B_ * HX_) + (size_t)b * HX_ + H_ + p)
            = pack4bf(xv.x, xv.y, xv.z, xv.w);
    } else if (idx < nx4 + B_ * H_ / 4) {           // zero slot-0 h-part
        const int k = (idx - nx4) * 4;
        const int b = k >> 10, p = k & 1023;
        *(ull*)(hxall + (size_t)b * HX_ + p) = 0ull;
    }
    if (idx < BAR_INTS) bar[idx] = 0u;
}

// ---- persistent LSTM: all 512 timesteps in one PLAIN-launched kernel ----
// Tiling, barrier, and sync structure are BYTE-IDENTICAL to the verified
// round-3 kernel (4102 us). Single change (v5): each wave's K-range is
// re-split into 256 h-cols (kq*256) + 128 x-cols (1024 + kq*128). The x-part
// of step t+1 (A loads + 4 MFMAs on init-staged data) executes BETWEEN the
// arrival flag store and the epoch wait -> hidden under barrier latency.
// Post-release critical path: 8 A-frag loads + 8 MFMAs (was 12+12).
__global__ __launch_bounds__(512, 4) void lstm_all(
    const short* __restrict__ Wp, const float* __restrict__ bp,
    short* __restrict__ hxall,            // [T_+1][B_][HX_] bf16
    unsigned* __restrict__ bar,
    float* __restrict__ out)              // [T_][B_][H_]
{
    __shared__ __align__(16) float red[4 * 32 * RP];

    const int tid  = threadIdx.x;
    const int bid  = blockIdx.x;          // 0..511
    const int nt   = bid & 255;
    const int mh   = bid >> 8;
    const int lane = tid & 63;
    const int wv   = tid >> 6;            // 0..7
    const int w    = wv & 1;
    const int kq   = wv >> 1;
    const int n16  = lane & 15;
    const int quad = lane >> 4;
    const int n0   = nt * 16;
    const int j0   = nt * 4;
    const int mrow = mh * 32 + w * 16 + n16;

    // Weights: load once, pinned for all 512 steps. 8 h-frags + 4 x-frags.
    bf16x8 bfh[8], bfx[4];
    {
        const short* brow = Wp + (size_t)(n0 + n16) * HX_ + quad * 8;
        #pragma unroll
        for (int f = 0; f < 8; ++f) bfh[f] = *(const bf16x8*)(brow + kq * 256 + f * 32);
        #pragma unroll
        for (int f = 0; f < 4; ++f) bfx[f] = *(const bf16x8*)(brow + 1024 + kq * 128 + f * 32);
    }

    // Epilogue-role constants (tid < 128): thread = (batch b_loc, unit j0+u)
    const int b_loc = tid >> 2;
    const int u     = tid & 3;
    const int gb    = mh * 32 + b_loc;
    const float4 bias = *(const float4*)(bp + n0 + u * 4);
    float c = 0.0f;

    // Running pointers (advance by one time-slot per step)
    const short* sp = hxall + (size_t)mrow * HX_ + quad * 8;                // A row base, slot t
    ull* hd = (ull*)(hxall + (size_t)(B_ * HX_) + (size_t)gb * HX_ + j0);   // h dst (slot t+1)
    float* op = out + (size_t)gb * H_ + j0 + u;

    unsigned* const flagp  = bar + (unsigned)bid * 32;                         // own line
    const unsigned* const epochp = bar + EPOCH_OFF + (mh * 8 + (bid & 7)) * 32; // shared hot line

    // x-phase for t=0 (x-part of A is init-staged for all t)
    floatx4 acc = {0.f, 0.f, 0.f, 0.f};
    {
        const short* ax = sp + 1024 + kq * 128;
        bf16x8 xa[4];
        #pragma unroll
        for (int f = 0; f < 4; ++f) xa[f] = *(const bf16x8*)(ax + f * 32);
        #pragma unroll
        for (int f = 0; f < 4; ++f)
            acc = __builtin_amdgcn_mfma_f32_16x16x32_bf16(xa[f], bfx[f], acc, 0, 0, 0);
    }

    for (int t = 0; t < T_; ++t) {
        // h-phase: 8 A-frag loads (depth-4 pipeline) + 8 MFMAs
        {
            const short* ah = sp + kq * 256;
            bf16x8 ha[4];
            #pragma unroll
            for (int i = 0; i < 4; ++i) ha[i] = *(const bf16x8*)(ah + i * 32);
            #pragma unroll
            for (int kf = 0; kf < 8; ++kf) {
                acc = __builtin_amdgcn_mfma_f32_16x16x32_bf16(ha[kf & 3], bfh[kf], acc, 0, 0, 0);
                if (kf + 4 < 8) ha[kf & 3] = *(const bf16x8*)(ah + (kf + 4) * 32);
            }
        }

        // C/D layout: col = lane&15, row = quad*4 + reg
        #pragma unroll
        for (int i2 = 0; i2 < 4; ++i2)
            red[(kq * 32 + w * 16 + quad * 4 + i2) * RP + n16] = acc[i2];
        __syncthreads();

        if (tid < 128) {
            float gv[4];
            #pragma unroll
            for (int gg = 0; gg < 4; ++gg) {
                const int col = u * 4 + gg;
                gv[gg] = red[(0 * 32 + b_loc) * RP + col]
                       + red[(1 * 32 + b_loc) * RP + col]
                       + red[(2 * 32 + b_loc) * RP + col]
                       + red[(3 * 32 + b_loc) * RP + col];
            }
            const float F  = sigmoidf_(gv[0] + bias.x);
            const float In = sigmoidf_(gv[1] + bias.y);
            const float G  = tanhf_(gv[2] + bias.z);
            const float O  = sigmoidf_(gv[3] + bias.w);
            c = F * c + In * G;
            const float h = O * tanhf_(c);
            *op = h;
            // gather the 4 units of this (batch, j0-block) into one 8B
            // device-coherent store (lanes u=0..3 are adjacent)
            const int hv = (int)(unsigned short)f2bf(h);
            const int base = lane & ~3;
            const int a0 = __shfl(hv, base + 0);
            const int a1 = __shfl(hv, base + 1);
            const int a2 = __shfl(hv, base + 2);
            const int a3 = __shfl(hv, base + 3);
            if (u == 0) {
                const ull pk = (ull)(unsigned)(unsigned short)a0
                             | ((ull)(unsigned)(unsigned short)a1 << 16)
                             | ((ull)(unsigned)(unsigned short)a2 << 32)
                             | ((ull)(unsigned)(unsigned short)a3 << 48);
                __hip_atomic_store(hd, pk, __ATOMIC_RELAXED, __HIP_MEMORY_SCOPE_AGENT);
            }
        }
        // Drain all stores (s_waitcnt vmcnt(0) before s_barrier), THEN arrive:
        // h is durable at the coherence point before the flag becomes visible.
        __syncthreads();

        if (t + 1 < T_) {
            const unsigned tgt = (unsigned)(t + 1);
            if (tid == 0)
                __hip_atomic_store(flagp, tgt, __ATOMIC_RELAXED,
                                   __HIP_MEMORY_SCOPE_AGENT);

            // x-phase for t+1 — overlapped with the barrier wait
            acc = floatx4{0.f, 0.f, 0.f, 0.f};
            {
                const short* ax = sp + (B_ * HX_) + 1024 + kq * 128;
                bf16x8 xa[4];
                #pragma unroll
                for (int f = 0; f < 4; ++f) xa[f] = *(const bf16x8*)(ax + f * 32);
                #pragma unroll
                for (int f = 0; f < 4; ++f)
                    acc = __builtin_amdgcn_mfma_f32_16x16x32_bf16(xa[f], bfx[f], acc, 0, 0, 0);
            }

            if (nt == 0) {
                // master: wave0 polls this group's 256 flags, 4 per lane
                if (tid < 64) {
                    const unsigned* f0 = bar + (mh * 256 + tid * 4) * 32;
                    for (unsigned it = 0; it < (1u << 16); ++it) {
                        const unsigned v0 = __hip_atomic_load(f0 +  0, __ATOMIC_RELAXED, __HIP_MEMORY_SCOPE_AGENT);
                        const unsigned v1 = __hip_atomic_load(f0 + 32, __ATOMIC_RELAXED, __HIP_MEMORY_SCOPE_AGENT);
                        const unsigned v2 = __hip_atomic_load(f0 + 64, __ATOMIC_RELAXED, __HIP_MEMORY_SCOPE_AGENT);
                        const unsigned v3 = __hip_atomic_load(f0 + 96, __ATOMIC_RELAXED, __HIP_MEMORY_SCOPE_AGENT);
                        const int ok = (v0 >= tgt) && (v1 >= tgt) && (v2 >= tgt) && (v3 >= tgt);
                        if (__all(ok)) break;
                        __builtin_amdgcn_s_sleep(1);
                    }
                    // broadcast release, replicated across 8 lines
                    if (tid < 8)
                        __hip_atomic_store(bar + EPOCH_OFF + (mh * 8 + tid) * 32, tgt,
                                           __ATOMIC_RELAXED, __HIP_MEMORY_SCOPE_AGENT);
                }
                __syncthreads();
            } else {
                if (tid == 0) {
                    for (unsigned it = 0; it < (1u << 16); ++it) {
                        if (__hip_atomic_load(epochp, __ATOMIC_RELAXED,
                                              __HIP_MEMORY_SCOPE_AGENT) >= tgt) break;
                        __builtin_amdgcn_s_sleep(1);
                    }
                }
                __syncthreads();
            }
        }

        sp += B_ * HX_;
        hd += (B_ * HX_) / 4;     // ull increments
        op += B_ * H_;
    }
}

// ================= fallback path (proven multi-launch kernels) =================

__global__ __launch_bounds__(256) void init_all(
    const float* __restrict__ x0, short* __restrict__ hx0, float* __restrict__ cws)
{
    int idx = blockIdx.x * 256 + threadIdx.x;
    if (idx < B_ * HX_) {
        int b = idx / HX_, p = idx % HX_;
        hx0[idx] = (p < H_) ? (short)0 : f2bf(x0[b * I_ + (p - H_)]);
    } else if (idx < B_ * HX_ + 512 * 128) {
        cws[idx - B_ * HX_] = 0.0f;
    }
}

__global__ __launch_bounds__(512, 4) void lstm_step(
    const short* __restrict__ Wp, const float* __restrict__ bp,
    const short* __restrict__ hxsrc, short* __restrict__ hxdst,
    const float* __restrict__ xnext, float* __restrict__ cws,
    float* __restrict__ out_t)
{
    __shared__ __align__(16) float red[4 * 32 * RP];

    const int tid  = threadIdx.x;
    const int nt   = blockIdx.x;
    const int mh   = blockIdx.y;
    const int lane = tid & 63;
    const int wv   = tid >> 6;
    const int w    = wv & 1;
    const int kq   = wv >> 1;
    const int n16  = lane & 15;
    const int quad = lane >> 4;
    const int n0   = nt * 16;
    const int j0   = nt * 4;
    const int mrow = mh * 32 + w * 16 + n16;

    const short* __restrict__ arow = hxsrc + mrow * HX_ + kq * 384 + quad * 8;
    const short* __restrict__ brow = Wp + (size_t)(n0 + n16) * HX_ + kq * 384 + quad * 8;

    bf16x8 bfr[12];
    #pragma unroll
    for (int i = 0; i < 12; ++i) bfr[i] = *(const bf16x8*)(brow + i * 32);
    bf16x8 afr[4];
    #pragma unroll
    for (int i = 0; i < 4; ++i) afr[i] = *(const bf16x8*)(arow + i * 32);

    floatx4 acc = {0.f, 0.f, 0.f, 0.f};
    #pragma unroll
    for (int kf = 0; kf < 12; ++kf) {
        acc = __builtin_amdgcn_mfma_f32_16x16x32_bf16(afr[kf & 3], bfr[kf], acc, 0, 0, 0);
        if (kf + 4 < 12) afr[kf & 3] = *(const bf16x8*)(arow + (kf + 4) * 32);
    }

    #pragma unroll
    for (int i2 = 0; i2 < 4; ++i2)
        red[(kq * 32 + w * 16 + quad * 4 + i2) * RP + n16] = acc[i2];
    __syncthreads();

    if (tid < 128) {
        const int b_loc = tid >> 2, u = tid & 3;
        float4 bias = *(const float4*)(bp + n0 + u * 4);
        float gv[4];
        #pragma unroll
        for (int gg = 0; gg < 4; ++gg) {
            const int col = u * 4 + gg;
            float s = red[(0 * 32 + b_loc) * RP + col]
                    + red[(1 * 32 + b_loc) * RP + col]
                    + red[(2 * 32 + b_loc) * RP + col]
                    + red[(3 * 32 + b_loc) * RP + col];
            gv[gg] = s;
        }
        float F  = sigmoidf_(gv[0] + bias.x);
        float In = sigmoidf_(gv[1] + bias.y);
        float G  = tanhf_(gv[2] + bias.z);
        float O  = sigmoidf_(gv[3] + bias.w);
        const int cidx = (mh * 256 + nt) * 128 + tid;
        float c = cws[cidx];
        c = F * c + In * G;
        cws[cidx] = c;
        float h = O * tanhf_(c);
        const int gb = mh * 32 + b_loc;
        out_t[(size_t)gb * H_ + j0 + u] = h;
        hxdst[gb * HX_ + j0 + u] = f2bf(h);
    } else if (tid < 192) {
        if (xnext) {
            const int e = (mh * 256 + nt) * 64 + (tid - 128);
            const int b = e >> 9, p = e & 511;
            hxdst[b * HX_ + H_ + p] = f2bf(xnext[e]);
        }
    }
}

// ================================ launcher ================================

extern "C" void kernel_launch(void* const* d_in, const int* in_sizes, int n_in,
                              void* d_out, int out_size, void* d_ws, size_t ws_size,
                              hipStream_t stream) {
    const float* x  = (const float*)d_in[0];
    const float* Wf = (const float*)d_in[1];
    const float* bf = (const float*)d_in[2];
    const float* Wi = (const float*)d_in[3];
    const float* bi = (const float*)d_in[4];
    const float* Wc = (const float*)d_in[5];
    const float* bc = (const float*)d_in[6];
    const float* Wo = (const float*)d_in[7];
    const float* bo = (const float*)d_in[8];
    float* out = (float*)d_out;

    // ws layout (bytes):
    //   Wp    : 4096*1536*2      = 12,582,912
    //   bp    : 4096*4           =     16,384
    //   bar   : 16896*4          =     67,584
    //   hx0/1 : 2*64*1536*2      =    393,216   (fallback)
    //   cws   : 512*128*4        =    262,144   (fallback)
    //   hxall : 513*64*1536*2    = 100,859,904  (persistent)  -> total ~114.2 MB
    char* wsb = (char*)d_ws;
    size_t off = 0;
    short*    Wp    = (short*)(wsb + off);    off += (size_t)NG * HX_ * 2;
    float*    bp    = (float*)(wsb + off);    off += (size_t)NG * 4;
    unsigned* bar   = (unsigned*)(wsb + off); off += (size_t)BAR_INTS * 4;
    short*    hx0   = (short*)(wsb + off);    off += (size_t)B_ * HX_ * 2;
    short*    hx1   = (short*)(wsb + off);    off += (size_t)B_ * HX_ * 2;
    float*    cws   = (float*)(wsb + off);    off += (size_t)512 * 128 * 4;
    short*    hxall = (short*)(wsb + off);
    const size_t need = off + (size_t)(T_ + 1) * B_ * HX_ * 2;

    pack_w<<<NG, 256, 0, stream>>>(Wf, Wi, Wc, Wo, bf, bi, bc, bo, Wp, bp);

    if (ws_size >= need) {
        const int nx4 = T_ * B_ * I_ / 4;
        init_hxall<<<(nx4 + B_ * H_ / 4 + 255) / 256, 256, 0, stream>>>(x, hxall, bar);
        lstm_all<<<dim3(NBLK), dim3(512), 0, stream>>>(Wp, bp, hxall, bar, out);
        return;
    }

    init_all<<<(B_ * HX_ + 512 * 128 + 255) / 256, 256, 0, stream>>>(x, hx0, cws);
    for (int t = 0; t < T_; ++t) {
        const short* hxsrc = (t & 1) ? hx1 : hx0;
        short*       hxdst = (t & 1) ? hx0 : hx1;
        const float* xnext = (t + 1 < T_) ? (x + (size_t)(t + 1) * B_ * I_) : nullptr;
        lstm_step<<<dim3(256, 2), 512, 0, stream>>>(
            Wp, bp, hxsrc, hxdst, xnext, cws,
            out + (size_t)t * B_ * H_);
    }
}

// Round 7
// 3278.987 us; speedup vs baseline: 2.1931x; 1.0494x over previous
//
#include <hip/hip_runtime.h>
#include <hip/hip_bf16.h>
#include <math.h>

// Problem dims (fixed by the reference)
#define T_  512
#define B_  64
#define I_  512
#define H_  1024
#define HX_ 1536
#define NG  4096          // 4*H packed gate rows
#define RP  17            // reduce-buffer pitch (fp32)
#define NBLK 512          // persistent grid: 2 blocks/CU * 256 CUs (co-resident by construction)

// Barrier layout (v7): COMPACT flags — flag[mh*256 + nt] is ONE dword.
// Each 256-flag group = 1KB = 8 cache lines. Arrivals are plain 4B agent
// stores to distinct dwords (no RMW); a polling wave covers its whole group
// with 4 dword loads/lane. Poll traffic ~2MB/round device-wide (8x under the
// round-6 flood; same pattern round 2 proved functional).
#define BAR_INTS  1024

typedef __attribute__((ext_vector_type(8))) short bf16x8;
typedef __attribute__((ext_vector_type(4))) float floatx4;
typedef unsigned long long ull;

__device__ __forceinline__ float sigmoidf_(float v) { return 1.0f / (1.0f + __expf(-v)); }
__device__ __forceinline__ float tanhf_(float v) {
    float e = __expf(-2.0f * fabsf(v));
    float t = (1.0f - e) / (1.0f + e);
    return copysignf(t, v);
}
__device__ __forceinline__ short f2bf(float f) {
    union { __hip_bfloat16 b; short s; } u;
    u.b = __float2bfloat16(f);   // RNE
    return u.s;
}
__device__ __forceinline__ ull pack4bf(float a, float b, float c, float d) {
    return (ull)(unsigned short)f2bf(a)
         | ((ull)(unsigned short)f2bf(b) << 16)
         | ((ull)(unsigned short)f2bf(c) << 32)
         | ((ull)(unsigned short)f2bf(d) << 48);
}

// ---- prologue: pack Wg -> Wp [4096][HX] bf16, rows r = u*4+g; biases too ----
__global__ __launch_bounds__(256) void pack_w(
    const float* __restrict__ Wf, const float* __restrict__ Wi,
    const float* __restrict__ Wc, const float* __restrict__ Wo,
    const float* __restrict__ bf, const float* __restrict__ bi,
    const float* __restrict__ bc, const float* __restrict__ bo,
    short* __restrict__ Wp, float* __restrict__ bp)
{
    const int r = blockIdx.x;          // 0..4095
    const int u = r >> 2, g = r & 3;
    const float* src; const float* bsrc;
    switch (g) {
        case 0:  src = Wf; bsrc = bf; break;
        case 1:  src = Wi; bsrc = bi; break;
        case 2:  src = Wc; bsrc = bc; break;
        default: src = Wo; bsrc = bo; break;
    }
    src += (size_t)u * HX_;
    for (int off = threadIdx.x; off < HX_; off += 256)
        Wp[(size_t)r * HX_ + off] = f2bf(src[off]);
    if (threadIdx.x == 0) bp[r] = bsrc[u];
}

// ---- persistent-path init: stage bf16(x_t) into hxall[t] x-part for ALL t,
//      zero hxall[0] h-part, zero barrier flags ----
__global__ __launch_bounds__(256) void init_hxall(
    const float* __restrict__ x, short* __restrict__ hxall, unsigned* __restrict__ bar)
{
    const int idx = blockIdx.x * 256 + threadIdx.x;
    const int nx4 = T_ * B_ * I_ / 4;               // 4,194,304 quads
    if (idx < nx4) {
        const int e = idx * 4;                      // element index into x
        const int t = e >> 15;                      // / (B_*I_)
        const int r = e & (B_ * I_ - 1);
        const int b = r >> 9, p = r & 511;
        const float4 xv = *(const float4*)(x + (size_t)e);
        *(ull*)(hxall + (size_t)t * (B_ * HX_) + (size_t)b * HX_ + H_ + p)
            = pack4bf(xv.x, xv.y, xv.z, xv.w);
    } else if (idx < nx4 + B_ * H_ / 4) {           // zero slot-0 h-part
        const int k = (idx - nx4) * 4;
        const int b = k >> 10, p = k & 1023;
        *(ull*)(hxall + (size_t)b * HX_ + p) = 0ull;
    }
    if (idx < BAR_INTS) bar[idx] = 0u;
}

// ---- persistent LSTM: all 512 timesteps in one PLAIN-launched kernel ----
// Tiling, x-phase overlap, and h-publication are BYTE-IDENTICAL to the
// verified round-5 kernel (3441 us). Single change (v7): flat ONE-HOP
// barrier over COMPACT flags. Arrive = 4B agent store to own dword.
// Every block's wave0 polls its group's 256 flag dwords (8 lines) with
// 4 loads/lane + __all vote + s_sleep(2); 4096-round watchdog (~1ms/step
// worst) -> terminates instead of hanging. Chain = store-visible + one
// load round (was 4 hops: flag, master-detect, epoch, waiter-detect).
__global__ __launch_bounds__(512, 4) void lstm_all(
    const short* __restrict__ Wp, const float* __restrict__ bp,
    short* __restrict__ hxall,            // [T_+1][B_][HX_] bf16
    unsigned* __restrict__ bar,
    float* __restrict__ out)              // [T_][B_][H_]
{
    __shared__ __align__(16) float red[4 * 32 * RP];

    const int tid  = threadIdx.x;
    const int bid  = blockIdx.x;          // 0..511
    const int nt   = bid & 255;
    const int mh   = bid >> 8;
    const int lane = tid & 63;
    const int wv   = tid >> 6;            // 0..7
    const int w    = wv & 1;
    const int kq   = wv >> 1;
    const int n16  = lane & 15;
    const int quad = lane >> 4;
    const int n0   = nt * 16;
    const int j0   = nt * 4;
    const int mrow = mh * 32 + w * 16 + n16;

    // Weights: load once, pinned for all 512 steps. 8 h-frags + 4 x-frags.
    bf16x8 bfh[8], bfx[4];
    {
        const short* brow = Wp + (size_t)(n0 + n16) * HX_ + quad * 8;
        #pragma unroll
        for (int f = 0; f < 8; ++f) bfh[f] = *(const bf16x8*)(brow + kq * 256 + f * 32);
        #pragma unroll
        for (int f = 0; f < 4; ++f) bfx[f] = *(const bf16x8*)(brow + 1024 + kq * 128 + f * 32);
    }

    // Epilogue-role constants (tid < 128): thread = (batch b_loc, unit j0+u)
    const int b_loc = tid >> 2;
    const int u     = tid & 3;
    const int gb    = mh * 32 + b_loc;
    const float4 bias = *(const float4*)(bp + n0 + u * 4);
    float c = 0.0f;

    // Running pointers (advance by one time-slot per step)
    const short* sp = hxall + (size_t)mrow * HX_ + quad * 8;                // A row base, slot t
    ull* hd = (ull*)(hxall + (size_t)(B_ * HX_) + (size_t)gb * HX_ + j0);   // h dst (slot t+1)
    float* op = out + (size_t)gb * H_ + j0 + u;

    unsigned* const flagp = bar + (unsigned)(mh * 256 + nt);                // own dword
    const unsigned* const pollp = bar + (unsigned)(mh * 256 + lane * 4);    // 4 dwords/lane

    // x-phase for t=0 (x-part of A is init-staged for all t)
    floatx4 acc = {0.f, 0.f, 0.f, 0.f};
    {
        const short* ax = sp + 1024 + kq * 128;
        bf16x8 xa[4];
        #pragma unroll
        for (int f = 0; f < 4; ++f) xa[f] = *(const bf16x8*)(ax + f * 32);
        #pragma unroll
        for (int f = 0; f < 4; ++f)
            acc = __builtin_amdgcn_mfma_f32_16x16x32_bf16(xa[f], bfx[f], acc, 0, 0, 0);
    }

    for (int t = 0; t < T_; ++t) {
        // h-phase: 8 A-frag loads (depth-4 pipeline) + 8 MFMAs
        {
            const short* ah = sp + kq * 256;
            bf16x8 ha[4];
            #pragma unroll
            for (int i = 0; i < 4; ++i) ha[i] = *(const bf16x8*)(ah + i * 32);
            #pragma unroll
            for (int kf = 0; kf < 8; ++kf) {
                acc = __builtin_amdgcn_mfma_f32_16x16x32_bf16(ha[kf & 3], bfh[kf], acc, 0, 0, 0);
                if (kf + 4 < 8) ha[kf & 3] = *(const bf16x8*)(ah + (kf + 4) * 32);
            }
        }

        // C/D layout: col = lane&15, row = quad*4 + reg
        #pragma unroll
        for (int i2 = 0; i2 < 4; ++i2)
            red[(kq * 32 + w * 16 + quad * 4 + i2) * RP + n16] = acc[i2];
        __syncthreads();

        if (tid < 128) {
            float gv[4];
            #pragma unroll
            for (int gg = 0; gg < 4; ++gg) {
                const int col = u * 4 + gg;
                gv[gg] = red[(0 * 32 + b_loc) * RP + col]
                       + red[(1 * 32 + b_loc) * RP + col]
                       + red[(2 * 32 + b_loc) * RP + col]
                       + red[(3 * 32 + b_loc) * RP + col];
            }
            const float F  = sigmoidf_(gv[0] + bias.x);
            const float In = sigmoidf_(gv[1] + bias.y);
            const float G  = tanhf_(gv[2] + bias.z);
            const float O  = sigmoidf_(gv[3] + bias.w);
            c = F * c + In * G;
            const float h = O * tanhf_(c);
            *op = h;
            // gather the 4 units of this (batch, j0-block) into one 8B
            // device-coherent store (lanes u=0..3 are adjacent)
            const int hv = (int)(unsigned short)f2bf(h);
            const int base = lane & ~3;
            const int a0 = __shfl(hv, base + 0);
            const int a1 = __shfl(hv, base + 1);
            const int a2 = __shfl(hv, base + 2);
            const int a3 = __shfl(hv, base + 3);
            if (u == 0) {
                const ull pk = (ull)(unsigned)(unsigned short)a0
                             | ((ull)(unsigned)(unsigned short)a1 << 16)
                             | ((ull)(unsigned)(unsigned short)a2 << 32)
                             | ((ull)(unsigned)(unsigned short)a3 << 48);
                __hip_atomic_store(hd, pk, __ATOMIC_RELAXED, __HIP_MEMORY_SCOPE_AGENT);
            }
        }
        // Drain all stores (s_waitcnt vmcnt(0) before s_barrier), THEN arrive:
        // h is durable at the coherence point before the flag becomes visible.
        __syncthreads();

        if (t + 1 < T_) {
            const unsigned tgt = (unsigned)(t + 1);
            if (tid == 0)
                __hip_atomic_store(flagp, tgt, __ATOMIC_RELAXED,
                                   __HIP_MEMORY_SCOPE_AGENT);

            // x-phase for t+1 — overlapped with the barrier wait
            acc = floatx4{0.f, 0.f, 0.f, 0.f};
            {
                const short* ax = sp + (B_ * HX_) + 1024 + kq * 128;
                bf16x8 xa[4];
                #pragma unroll
                for (int f = 0; f < 4; ++f) xa[f] = *(const bf16x8*)(ax + f * 32);
                #pragma unroll
                for (int f = 0; f < 4; ++f)
                    acc = __builtin_amdgcn_mfma_f32_16x16x32_bf16(xa[f], bfx[f], acc, 0, 0, 0);
            }

            // FLAT one-hop barrier over compact flags: wave0 scans the
            // group's 256 dwords (8 cache lines), 4 contiguous dwords/lane.
            if (tid < 64) {
                for (unsigned it = 0; it < 4096u; ++it) {
                    const unsigned v0 = __hip_atomic_load(pollp + 0, __ATOMIC_RELAXED, __HIP_MEMORY_SCOPE_AGENT);
                    const unsigned v1 = __hip_atomic_load(pollp + 1, __ATOMIC_RELAXED, __HIP_MEMORY_SCOPE_AGENT);
                    const unsigned v2 = __hip_atomic_load(pollp + 2, __ATOMIC_RELAXED, __HIP_MEMORY_SCOPE_AGENT);
                    const unsigned v3 = __hip_atomic_load(pollp + 3, __ATOMIC_RELAXED, __HIP_MEMORY_SCOPE_AGENT);
                    const int ok = (v0 >= tgt) && (v1 >= tgt) && (v2 >= tgt) && (v3 >= tgt);
                    if (__all(ok)) break;
                    __builtin_amdgcn_s_sleep(2);
                }
            }
            __syncthreads();
        }

        sp += B_ * HX_;
        hd += (B_ * HX_) / 4;     // ull increments
        op += B_ * H_;
    }
}

// ================= fallback path (proven multi-launch kernels) =================

__global__ __launch_bounds__(256) void init_all(
    const float* __restrict__ x0, short* __restrict__ hx0, float* __restrict__ cws)
{
    int idx = blockIdx.x * 256 + threadIdx.x;
    if (idx < B_ * HX_) {
        int b = idx / HX_, p = idx % HX_;
        hx0[idx] = (p < H_) ? (short)0 : f2bf(x0[b * I_ + (p - H_)]);
    } else if (idx < B_ * HX_ + 512 * 128) {
        cws[idx - B_ * HX_] = 0.0f;
    }
}

__global__ __launch_bounds__(512, 4) void lstm_step(
    const short* __restrict__ Wp, const float* __restrict__ bp,
    const short* __restrict__ hxsrc, short* __restrict__ hxdst,
    const float* __restrict__ xnext, float* __restrict__ cws,
    float* __restrict__ out_t)
{
    __shared__ __align__(16) float red[4 * 32 * RP];

    const int tid  = threadIdx.x;
    const int nt   = blockIdx.x;
    const int mh   = blockIdx.y;
    const int lane = tid & 63;
    const int wv   = tid >> 6;
    const int w    = wv & 1;
    const int kq   = wv >> 1;
    const int n16  = lane & 15;
    const int quad = lane >> 4;
    const int n0   = nt * 16;
    const int j0   = nt * 4;
    const int mrow = mh * 32 + w * 16 + n16;

    const short* __restrict__ arow = hxsrc + mrow * HX_ + kq * 384 + quad * 8;
    const short* __restrict__ brow = Wp + (size_t)(n0 + n16) * HX_ + kq * 384 + quad * 8;

    bf16x8 bfr[12];
    #pragma unroll
    for (int i = 0; i < 12; ++i) bfr[i] = *(const bf16x8*)(brow + i * 32);
    bf16x8 afr[4];
    #pragma unroll
    for (int i = 0; i < 4; ++i) afr[i] = *(const bf16x8*)(arow + i * 32);

    floatx4 acc = {0.f, 0.f, 0.f, 0.f};
    #pragma unroll
    for (int kf = 0; kf < 12; ++kf) {
        acc = __builtin_amdgcn_mfma_f32_16x16x32_bf16(afr[kf & 3], bfr[kf], acc, 0, 0, 0);
        if (kf + 4 < 12) afr[kf & 3] = *(const bf16x8*)(arow + (kf + 4) * 32);
    }

    #pragma unroll
    for (int i2 = 0; i2 < 4; ++i2)
        red[(kq * 32 + w * 16 + quad * 4 + i2) * RP + n16] = acc[i2];
    __syncthreads();

    if (tid < 128) {
        const int b_loc = tid >> 2, u = tid & 3;
        float4 bias = *(const float4*)(bp + n0 + u * 4);
        float gv[4];
        #pragma unroll
        for (int gg = 0; gg < 4; ++gg) {
            const int col = u * 4 + gg;
            float s = red[(0 * 32 + b_loc) * RP + col]
                    + red[(1 * 32 + b_loc) * RP + col]
                    + red[(2 * 32 + b_loc) * RP + col]
                    + red[(3 * 32 + b_loc) * RP + col];
            gv[gg] = s;
        }
        float F  = sigmoidf_(gv[0] + bias.x);
        float In = sigmoidf_(gv[1] + bias.y);
        float G  = tanhf_(gv[2] + bias.z);
        float O  = sigmoidf_(gv[3] + bias.w);
        const int cidx = (mh * 256 + nt) * 128 + tid;
        float c = cws[cidx];
        c = F * c + In * G;
        cws[cidx] = c;
        float h = O * tanhf_(c);
        const int gb = mh * 32 + b_loc;
        out_t[(size_t)gb * H_ + j0 + u] = h;
        hxdst[gb * HX_ + j0 + u] = f2bf(h);
    } else if (tid < 192) {
        if (xnext) {
            const int e = (mh * 256 + nt) * 64 + (tid - 128);
            const int b = e >> 9, p = e & 511;
            hxdst[b * HX_ + H_ + p] = f2bf(xnext[e]);
        }
    }
}

// ================================ launcher ================================

extern "C" void kernel_launch(void* const* d_in, const int* in_sizes, int n_in,
                              void* d_out, int out_size, void* d_ws, size_t ws_size,
                              hipStream_t stream) {
    const float* x  = (const float*)d_in[0];
    const float* Wf = (const float*)d_in[1];
    const float* bf = (const float*)d_in[2];
    const float* Wi = (const float*)d_in[3];
    const float* bi = (const float*)d_in[4];
    const float* Wc = (const float*)d_in[5];
    const float* bc = (const float*)d_in[6];
    const float* Wo = (const float*)d_in[7];
    const float* bo = (const float*)d_in[8];
    float* out = (float*)d_out;

    // ws layout (bytes):
    //   Wp    : 4096*1536*2      = 12,582,912
    //   bp    : 4096*4           =     16,384
    //   bar   : 1024*4           =      4,096
    //   hx0/1 : 2*64*1536*2      =    393,216   (fallback)
    //   cws   : 512*128*4        =    262,144   (fallback)
    //   hxall : 513*64*1536*2    = 100,859,904  (persistent)  -> total ~114.1 MB
    char* wsb = (char*)d_ws;
    size_t off = 0;
    short*    Wp    = (short*)(wsb + off);    off += (size_t)NG * HX_ * 2;
    float*    bp    = (float*)(wsb + off);    off += (size_t)NG * 4;
    unsigned* bar   = (unsigned*)(wsb + off); off += (size_t)BAR_INTS * 4;
    short*    hx0   = (short*)(wsb + off);    off += (size_t)B_ * HX_ * 2;
    short*    hx1   = (short*)(wsb + off);    off += (size_t)B_ * HX_ * 2;
    float*    cws   = (float*)(wsb + off);    off += (size_t)512 * 128 * 4;
    short*    hxall = (short*)(wsb + off);
    const size_t need = off + (size_t)(T_ + 1) * B_ * HX_ * 2;

    pack_w<<<NG, 256, 0, stream>>>(Wf, Wi, Wc, Wo, bf, bi, bc, bo, Wp, bp);

    if (ws_size >= need) {
        const int nx4 = T_ * B_ * I_ / 4;
        init_hxall<<<(nx4 + B_ * H_ / 4 + 255) / 256, 256, 0, stream>>>(x, hxall, bar);
        lstm_all<<<dim3(NBLK), dim3(512), 0, stream>>>(Wp, bp, hxall, bar, out);
        return;
    }

    init_all<<<(B_ * HX_ + 512 * 128 + 255) / 256, 256, 0, stream>>>(x, hx0, cws);
    for (int t = 0; t < T_; ++t) {
        const short* hxsrc = (t & 1) ? hx1 : hx0;
        short*       hxdst = (t & 1) ? hx0 : hx1;
        const float* xnext = (t + 1 < T_) ? (x + (size_t)(t + 1) * B_ * I_) : nullptr;
        lstm_step<<<dim3(256, 2), 512, 0, stream>>>(
            Wp, bp, hxsrc, hxdst, xnext, cws,
            out + (size_t)t * B_ * H_);
    }
}